// Round 9
// baseline (2372.937 us; speedup 1.0000x reference)
//
#include <hip/hip_runtime.h>

#define N_NODES   100000
#define D_IN      512
#define NUM_CODES 2048
#define D_OUT     256
#define NCAND     16
#define RESCORE_MARGIN 0.05f
#define TSPLIT    780   // packed-Hb tiles [0,780) in d_out, [780,782) in ws tail

typedef float f32x4  __attribute__((ext_vector_type(4)));
typedef short bf16x8 __attribute__((ext_vector_type(8)));

__device__ __forceinline__ bool better(float s, int i, float S, int I) {
  return (s < S) || (s == S && i < I);
}

__device__ __forceinline__ unsigned short f2bf(float f) {
  unsigned int u = __float_as_uint(f);
  u = (u + 0x7fffu + ((u >> 16) & 1u)) >> 16;  // RNE
  return (unsigned short)u;
}

// packed fragment layout (Hb and CBb), MFMA-native:
//   piece (tile t, granule g in [0,16), row-group rg in [0,8), lane=quad*16+l16)
//   at byte t*131072 + g*8192 + rg*1024 + lane*16
//   holds elements (row = rg*16 + l16, k = g*32 + quad*8 + e), e in [0,8) bf16.
// A wave's MFMA fragment (16 rows x K=32) == one contiguous 1KB line.

// ---------------------------------------------------------------------------
// numpy pairwise sum-of-squares over a 512-float row (np-exact; see r3).
// ---------------------------------------------------------------------------
__device__ __forceinline__ float np_pairwise_sq512(const float* __restrict__ a) {
  float tot[4];
#pragma unroll
  for (int b = 0; b < 4; b++) {
    const float* p = a + (b << 7);
    float r[8];
    {
      float4 q0 = *(const float4*)(p);
      float4 q1 = *(const float4*)(p + 4);
      r[0] = __fmul_rn(q0.x, q0.x); r[1] = __fmul_rn(q0.y, q0.y);
      r[2] = __fmul_rn(q0.z, q0.z); r[3] = __fmul_rn(q0.w, q0.w);
      r[4] = __fmul_rn(q1.x, q1.x); r[5] = __fmul_rn(q1.y, q1.y);
      r[6] = __fmul_rn(q1.z, q1.z); r[7] = __fmul_rn(q1.w, q1.w);
    }
    for (int i = 8; i < 128; i += 8) {
      float4 u0 = *(const float4*)(p + i);
      float4 u1 = *(const float4*)(p + i + 4);
      r[0] = __fadd_rn(r[0], __fmul_rn(u0.x, u0.x));
      r[1] = __fadd_rn(r[1], __fmul_rn(u0.y, u0.y));
      r[2] = __fadd_rn(r[2], __fmul_rn(u0.z, u0.z));
      r[3] = __fadd_rn(r[3], __fmul_rn(u0.w, u0.w));
      r[4] = __fadd_rn(r[4], __fmul_rn(u1.x, u1.x));
      r[5] = __fadd_rn(r[5], __fmul_rn(u1.y, u1.y));
      r[6] = __fadd_rn(r[6], __fmul_rn(u1.z, u1.z));
      r[7] = __fadd_rn(r[7], __fmul_rn(u1.w, u1.w));
    }
    float t01 = __fadd_rn(r[0], r[1]);
    float t23 = __fadd_rn(r[2], r[3]);
    float t45 = __fadd_rn(r[4], r[5]);
    float t67 = __fadd_rn(r[6], r[7]);
    tot[b] = __fadd_rn(__fadd_rn(t01, t23), __fadd_rn(t45, t67));
  }
  return __fadd_rn(__fadd_rn(tot[0], tot[1]), __fadd_rn(tot[2], tot[3]));
}

__global__ __launch_bounds__(256) void k_rowsq(const float* __restrict__ A,
                                               int nrows,
                                               float* __restrict__ out) {
  int r = blockIdx.x * 256 + threadIdx.x;
  if (r >= nrows) return;
  out[r] = np_pairwise_sq512(A + (size_t)r * D_IN);
}

// ---------------------------------------------------------------------------
// CBbP = bf16(CB) in packed fragment layout. 131072 pieces of 16B.
// piece id: code = id>>6, j = id&63 (8-k piece): g = j>>2, quad = j&3.
// ---------------------------------------------------------------------------
__global__ __launch_bounds__(256) void k_cb2bf(const float* __restrict__ CB,
                                               char* __restrict__ CBbP) {
  int id = blockIdx.x * 256 + threadIdx.x;  // [0, 131072)
  int code = id >> 6, j = id & 63;
  int g = j >> 2, quad = j & 3;
  int ct = code >> 7, lc = code & 127;
  int cf = lc >> 4, l16 = lc & 15;
  const float* src = CB + (size_t)code * D_IN + (j << 3);
  float4 v0 = *(const float4*)src;
  float4 v1 = *(const float4*)(src + 4);
  unsigned int w0 = (unsigned)f2bf(v0.x) | ((unsigned)f2bf(v0.y) << 16);
  unsigned int w1 = (unsigned)f2bf(v0.z) | ((unsigned)f2bf(v0.w) << 16);
  unsigned int w2 = (unsigned)f2bf(v1.x) | ((unsigned)f2bf(v1.y) << 16);
  unsigned int w3 = (unsigned)f2bf(v1.z) | ((unsigned)f2bf(v1.w) << 16);
  *(uint4*)(CBbP + (size_t)ct * 131072 + g * 8192 + cf * 1024 + quad * 256 +
            l16 * 16) = make_uint4(w0, w1, w2, w3);
}

// ---------------------------------------------------------------------------
// H = X @ LP (np-exact fp32: per-output single sequential-k FMA chain,
// kk = 0..511 ascending -> bit-identical to prior versions; tiling does not
// change the chain). v2: 128x128 tile, 8x8 per thread (halves LDS traffic
// per FLOP vs 64x64/4x4). Also emits packed-fragment bf16(H).
// ---------------------------------------------------------------------------
__global__ __launch_bounds__(256) void k_h_np(const float* __restrict__ X,
                                              const float* __restrict__ W,
                                              float* __restrict__ H,
                                              char* __restrict__ HbMain,
                                              char* __restrict__ HbTail) {
  __shared__ float As[16][132];
  __shared__ float Bs[16][132];
  const int tid = threadIdx.x;
  const int row0 = blockIdx.x * 128;
  const int col0 = blockIdx.y * 128;
  const int ty = tid >> 4, tx = tid & 15;
  const int ar = tid >> 2, ak = (tid & 3) << 2;   // A tasks: tid, tid+256
  const int bk = tid >> 5, bn = (tid & 31) << 2;  // B tasks: tid, tid+256
  float acc[8][8] = {};
  for (int k0 = 0; k0 < D_IN; k0 += 16) {
    float4 av0 = make_float4(0.f, 0.f, 0.f, 0.f), av1 = av0;
    if (row0 + ar < N_NODES)
      av0 = *(const float4*)(X + (size_t)(row0 + ar) * D_IN + k0 + ak);
    if (row0 + ar + 64 < N_NODES)
      av1 = *(const float4*)(X + (size_t)(row0 + ar + 64) * D_IN + k0 + ak);
    float4 bv0 = *(const float4*)(W + (size_t)(k0 + bk) * D_IN + col0 + bn);
    float4 bv1 = *(const float4*)(W + (size_t)(k0 + bk + 8) * D_IN + col0 + bn);
    __syncthreads();
    As[ak + 0][ar] = av0.x; As[ak + 1][ar] = av0.y;
    As[ak + 2][ar] = av0.z; As[ak + 3][ar] = av0.w;
    As[ak + 0][ar + 64] = av1.x; As[ak + 1][ar + 64] = av1.y;
    As[ak + 2][ar + 64] = av1.z; As[ak + 3][ar + 64] = av1.w;
    *(float4*)&Bs[bk][bn] = bv0;
    *(float4*)&Bs[bk + 8][bn] = bv1;
    __syncthreads();
#pragma unroll
    for (int kk = 0; kk < 16; kk++) {  // strictly increasing k
      float a8[8], b8[8];
      *(float4*)&a8[0] = *(const float4*)&As[kk][ty * 8];
      *(float4*)&a8[4] = *(const float4*)&As[kk][ty * 8 + 4];
      *(float4*)&b8[0] = *(const float4*)&Bs[kk][tx * 8];
      *(float4*)&b8[4] = *(const float4*)&Bs[kk][tx * 8 + 4];
#pragma unroll
      for (int i = 0; i < 8; i++)
#pragma unroll
        for (int j = 0; j < 8; j++) acc[i][j] = fmaf(a8[i], b8[j], acc[i][j]);
    }
  }
  const int t = blockIdx.x;
  char* base = (t < TSPLIT) ? (HbMain + (size_t)t * 131072)
                            : (HbTail + (size_t)(t - TSPLIT) * 131072);
  const int c0 = col0 + tx * 8;  // 8 consecutive k == one 16B piece
  const int gq = (c0 >> 5) * 8192 + ((c0 >> 3) & 3) * 256;
#pragma unroll
  for (int i = 0; i < 8; i++) {
    int r = row0 + ty * 8 + i;
    if (r < N_NODES) {
      float* hp = H + (size_t)r * D_IN + c0;
      *(float4*)hp = make_float4(acc[i][0], acc[i][1], acc[i][2], acc[i][3]);
      *(float4*)(hp + 4) =
          make_float4(acc[i][4], acc[i][5], acc[i][6], acc[i][7]);
      unsigned int w0 = (unsigned)f2bf(acc[i][0]) | ((unsigned)f2bf(acc[i][1]) << 16);
      unsigned int w1 = (unsigned)f2bf(acc[i][2]) | ((unsigned)f2bf(acc[i][3]) << 16);
      unsigned int w2 = (unsigned)f2bf(acc[i][4]) | ((unsigned)f2bf(acc[i][5]) << 16);
      unsigned int w3 = (unsigned)f2bf(acc[i][6]) | ((unsigned)f2bf(acc[i][7]) << 16);
      int rl = r & 127;
      *(uint4*)(base + gq + ((rl >> 4) << 10) + ((rl & 15) << 4)) =
          make_uint4(w0, w1, w2, w3);
    }
  }
}

// ---------------------------------------------------------------------------
// P[c][o] = CB[c]·HW[:,o] in fp64 (stored fp32). Logit path only.
// ---------------------------------------------------------------------------
__global__ __launch_bounds__(256) void k_gemm_P(const float* __restrict__ CB,
                                                const float* __restrict__ HW,
                                                float* __restrict__ P) {
  __shared__ float As[16][68];
  __shared__ float Bs[16][68];
  const int tid = threadIdx.x;
  const int c0 = blockIdx.x * 64;
  const int o0 = blockIdx.y * 64;
  const int ty = tid >> 4, tx = tid & 15;
  const int am = tid >> 2, ak = (tid & 3) << 2;
  const int bk = tid >> 4, bn = (tid & 15) << 2;
  double acc[4][4] = {};
  for (int k0 = 0; k0 < D_IN; k0 += 16) {
    float4 av = *(const float4*)(CB + (size_t)(c0 + am) * D_IN + k0 + ak);
    float4 bv = *(const float4*)(HW + (size_t)(k0 + bk) * D_OUT + o0 + bn);
    __syncthreads();
    As[ak + 0][am] = av.x; As[ak + 1][am] = av.y;
    As[ak + 2][am] = av.z; As[ak + 3][am] = av.w;
    *(float4*)&Bs[bk][bn] = bv;
    __syncthreads();
#pragma unroll
    for (int kk = 0; kk < 16; kk++) {
      float4 a = *(const float4*)&As[kk][ty << 2];
      float4 b = *(const float4*)&Bs[kk][tx << 2];
      double aa[4] = {a.x, a.y, a.z, a.w};
      double bb[4] = {b.x, b.y, b.z, b.w};
#pragma unroll
      for (int i = 0; i < 4; i++)
#pragma unroll
        for (int j = 0; j < 4; j++) acc[i][j] = fma(aa[i], bb[j], acc[i][j]);
    }
  }
#pragma unroll
  for (int i = 0; i < 4; i++)
#pragma unroll
    for (int j = 0; j < 4; j++)
      P[(size_t)(c0 + (ty << 2) + i) * D_OUT + o0 + (tx << 2) + j] =
          (float)acc[i][j];
}

// ---------------------------------------------------------------------------
// MFMA candidate pass v7: A-IN-REGISTERS + DIRECT-L2 B. No LDS staging, no
// barriers in the K-loop. Each of 4 waves owns 32 rows (af[2][16], loaded
// once); B fragments read as coalesced 1KB global loads from the packed
// L2-resident codebook. MFMA chain per (row,code) = 16 ascending K=32
// granules == all prior versions -> scores bit-identical. Score/scan = v3
// verbatim (Sc[128][128] swizzled, 256 scanners, strict <, ascending code).
// LDS = Sc only (64KB). 2 syncthreads per ct (vs 19).
// ---------------------------------------------------------------------------
__global__ __launch_bounds__(256, 2) void k_mfma_cand(
    const char* __restrict__ HbMain, const char* __restrict__ HbTail,
    const char* __restrict__ CBbP, const float* __restrict__ CBSQ,
    float* __restrict__ candS, int* __restrict__ candI) {
  __shared__ __align__(16) float Sc[128 * 128];  // 64 KB
  const int tid  = threadIdx.x;
  const int lane = tid & 63, wave = tid >> 6;
  const int quad = lane >> 4, l16 = lane & 15;
  const int t = blockIdx.x;
  const int row0 = t * 128;
  const int srow = tid >> 1, shalf = tid & 1;
  const int loff = lane * 16;

  const char* tb = (t < TSPLIT) ? (HbMain + (size_t)t * 131072)
                                : (HbTail + (size_t)(t - TSPLIT) * 131072);

  // A fragments for this wave's 32 rows (row-groups 2w, 2w+1), all K.
  bf16x8 af[2][16];
#pragma unroll
  for (int g = 0; g < 16; g++) {
#pragma unroll
    for (int i = 0; i < 2; i++)
      af[i][g] =
          *(const bf16x8*)(tb + g * 8192 + (wave * 2 + i) * 1024 + loff);
  }

  float rs[8]; int ri[8];
#pragma unroll
  for (int k = 0; k < 8; k++) { rs[k] = 3.4e38f; ri[k] = 0x7fffffff; }

  for (int ct = 0; ct < NUM_CODES / 128; ct++) {
    const int code0 = ct * 128;
    const char* gB = CBbP + (size_t)ct * 131072;
    f32x4 acc[2][8];
#pragma unroll
    for (int i = 0; i < 2; i++)
#pragma unroll
      for (int cf = 0; cf < 8; cf++) acc[i][cf] = (f32x4){0.f, 0.f, 0.f, 0.f};

    // K-loop: barrier-free. 8 coalesced B loads + 16 MFMA per granule.
#pragma unroll
    for (int g = 0; g < 16; g++) {
      bf16x8 bf[8];
#pragma unroll
      for (int cf = 0; cf < 8; cf++)
        bf[cf] = *(const bf16x8*)(gB + g * 8192 + cf * 1024 + loff);
#pragma unroll
      for (int i = 0; i < 2; i++)
#pragma unroll
        for (int cf = 0; cf < 8; cf++)
          acc[i][cf] = __builtin_amdgcn_mfma_f32_16x16x32_bf16(
              af[i][g], bf[cf], acc[i][cf], 0, 0, 0);
    }

    __syncthreads();  // previous scan done -> Sc overwritable
    // scores -> Sc[row][128], v3 swizzle. C/D: col=lane&15, row=quad*4+r.
#pragma unroll
    for (int cf = 0; cf < 8; cf++) {
      int lc = cf * 16 + l16;
      float cq = CBSQ[code0 + lc];
      int g2 = lc >> 2, e = lc & 3;
#pragma unroll
      for (int i = 0; i < 2; i++) {
        int rowb = wave * 32 + i * 16 + quad * 4;
#pragma unroll
        for (int r = 0; r < 4; r++) {
          float s = fmaf(-2.0f, acc[i][cf][r], cq);
          int row = rowb + r;
          int p = (g2 & 24) | ((g2 ^ row) & 7);
          Sc[row * 128 + p * 4 + e] = s;
        }
      }
    }
    __syncthreads();
    // scan: thread (srow, shalf): preload 16 f32x4 (visit-swizzled), then
    // min group-reject + insertion (strict <, ascending code order).
    f32x4 vv[16];
    const float* rowbase = Sc + srow * 128;
#pragma unroll
    for (int j = 0; j < 16; j++) {
      int g2 = shalf * 16 + j;
      int p = (g2 & 24) | ((g2 ^ srow) & 7);
      vv[j] = *(const f32x4*)(rowbase + p * 4);
    }
#pragma unroll
    for (int j = 0; j < 16; j++) {
      f32x4 v = vv[j];
      float mn = fminf(fminf(v[0], v[1]), fminf(v[2], v[3]));
      if (mn < rs[7]) {
        int cb = code0 + shalf * 64 + (j << 2);
#pragma unroll
        for (int e = 0; e < 4; e++) {
          if (v[e] < rs[7]) {
            rs[7] = v[e]; ri[7] = cb + e;
#pragma unroll
            for (int t2 = 7; t2 > 0; t2--) {
              if (rs[t2] < rs[t2 - 1]) {
                float tf = rs[t2 - 1]; rs[t2 - 1] = rs[t2]; rs[t2] = tf;
                int tc = ri[t2 - 1]; ri[t2 - 1] = ri[t2]; ri[t2] = tc;
              }
            }
          }
        }
      }
    }
  }
  int grow = row0 + srow;
  if (grow < N_NODES) {
#pragma unroll
    for (int k = 0; k < 8; k++) {
      candS[(size_t)grow * NCAND + shalf * 8 + k] = rs[k];
      candI[(size_t)grow * NCAND + shalf * 8 + k] = ri[k];
    }
  }
}

// ---------------------------------------------------------------------------
// np-exact rescore of candidates within RESCORE_MARGIN of the 4th-best approx
// score; exact fp32 sequential-k chain + np combine; top-4 (ties->lower idx).
// Block: 16 rows x 16 candidates.
// ---------------------------------------------------------------------------
__global__ __launch_bounds__(256) void k_rescore(
    const float* __restrict__ H, const float* __restrict__ CB,
    const float* __restrict__ CBSQ, const float* __restrict__ HSQ,
    const float* __restrict__ candS, const int* __restrict__ candI,
    int* __restrict__ cand4) {
  __shared__ float hs[16][516];
  __shared__ float ss[16][16];
  __shared__ int   ii[16][16];
  __shared__ float sres[16][16];
  const int tid = threadIdx.x;
  const int r0 = blockIdx.x * 16;
#pragma unroll
  for (int it = 0; it < 8; it++) {  // 2048 float4 tasks: coop-load 16 H rows
    int id = tid + it * 256;
    int row = id >> 7, f4 = id & 127;
    float4 v = *(const float4*)(H + (size_t)(r0 + row) * D_IN + f4 * 4);
    *(float4*)&hs[row][f4 * 4] = v;
  }
  {
    int row = tid >> 4, j = tid & 15;
    ss[row][j] = candS[(size_t)(r0 + row) * NCAND + j];
    ii[row][j] = candI[(size_t)(r0 + row) * NCAND + j];
  }
  __syncthreads();
  const int row = tid >> 4, j = tid & 15;
  // 4th-smallest approx score of this row's 16 candidates
  float m[4] = {3.4e38f, 3.4e38f, 3.4e38f, 3.4e38f};
  for (int t = 0; t < 16; t++) {
    float s = ss[row][t];
    if (s < m[3]) {
      m[3] = s;
#pragma unroll
      for (int u = 3; u > 0; u--)
        if (m[u] < m[u - 1]) { float tt = m[u - 1]; m[u - 1] = m[u]; m[u] = tt; }
    }
  }
  const float thr = m[3] + RESCORE_MARGIN;
  const float as = ss[row][j];
  const int ci = ii[row][j];
  float sc = 3.4e38f;
  if (as <= thr) {
    const float4* cbp = (const float4*)(CB + (size_t)ci * D_IN);
    float d = 0.f;
    for (int k = 0; k < 128; k++) {  // strict k order: single FMA chain
      float4 c4 = cbp[k];
      float4 h4 = *(const float4*)&hs[row][k * 4];
      d = fmaf(h4.x, c4.x, d);
      d = fmaf(h4.y, c4.y, d);
      d = fmaf(h4.z, c4.z, d);
      d = fmaf(h4.w, c4.w, d);
    }
    float t1 = __fsub_rn(HSQ[r0 + row], 2.0f * d);  // 2*d exact
    sc = __fadd_rn(t1, CBSQ[ci]);                   // np combine order
  }
  sres[row][j] = sc;
  __syncthreads();
  if (j == 0) {
    float bs[4]; int bi[4];
#pragma unroll
    for (int k = 0; k < 4; k++) { bs[k] = 3.4e38f; bi[k] = 0x7fffffff; }
    for (int t = 0; t < 16; t++) {
      float s = sres[row][t]; int c = ii[row][t];
      if (better(s, c, bs[3], bi[3])) {
        bs[3] = s; bi[3] = c;
#pragma unroll
        for (int u = 3; u > 0; u--) {
          if (better(bs[u], bi[u], bs[u - 1], bi[u - 1])) {
            float tf = bs[u - 1]; bs[u - 1] = bs[u]; bs[u] = tf;
            int tc = bi[u - 1]; bi[u - 1] = bi[u]; bi[u] = tc;
          }
        }
      }
    }
#pragma unroll
    for (int k = 0; k < 4; k++) cand4[(size_t)(r0 + row) * 4 + k] = bi[k];
  }
}

// ---------------------------------------------------------------------------
// OUT[row] = 0.25 * (P[c0]+P[c1]+P[c2]+P[c3]) + bias. One wave per row.
// ---------------------------------------------------------------------------
__global__ __launch_bounds__(256) void k_out(const int* __restrict__ cand4,
                                             const float* __restrict__ P,
                                             const float* __restrict__ HB,
                                             float* __restrict__ OUT) {
  const int lane = threadIdx.x & 63;
  const int row = blockIdx.x * 4 + (threadIdx.x >> 6);
  if (row >= N_NODES) return;
  const int c0 = cand4[(size_t)row * 4 + 0];
  const int c1 = cand4[(size_t)row * 4 + 1];
  const int c2 = cand4[(size_t)row * 4 + 2];
  const int c3 = cand4[(size_t)row * 4 + 3];
  const int col = lane << 2;
  float4 p0 = *(const float4*)(P + (size_t)c0 * D_OUT + col);
  float4 p1 = *(const float4*)(P + (size_t)c1 * D_OUT + col);
  float4 p2 = *(const float4*)(P + (size_t)c2 * D_OUT + col);
  float4 p3 = *(const float4*)(P + (size_t)c3 * D_OUT + col);
  float4 b = *(const float4*)(HB + col);
  float4 o;
  o.x = 0.25f * (((p0.x + p1.x) + p2.x) + p3.x) + b.x;
  o.y = 0.25f * (((p0.y + p1.y) + p2.y) + p3.y) + b.y;
  o.z = 0.25f * (((p0.z + p1.z) + p2.z) + p3.z) + b.z;
  o.w = 0.25f * (((p0.w + p1.w) + p2.w) + p3.w) + b.w;
  *(float4*)(OUT + (size_t)row * D_OUT + col) = o;
}

// ---------------------------------------------------------------------------
extern "C" void kernel_launch(void* const* d_in, const int* in_sizes, int n_in,
                              void* d_out, int out_size, void* d_ws,
                              size_t ws_size, hipStream_t stream) {
  const float* X  = (const float*)d_in[0];
  const float* LP = (const float*)d_in[1];
  const float* CB = (const float*)d_in[2];
  const float* HW = (const float*)d_in[3];
  const float* HB = (const float*)d_in[4];
  float* OUT = (float*)d_out;

  // d_out (102.4 MB) holds packed Hb tiles [0,TSPLIT); the last 2 tiles
  // (256 KB) live in ws tail. Fully consumed by k_mfma_cand before k_out
  // overwrites.
  char* HbMain = (char*)d_out;

  char* ws = (char*)d_ws;
  size_t off = 0;
  float* H = (float*)(ws + off);      off += (size_t)N_NODES * D_IN * 4;     // 204.8 MB
  float* P = (float*)(ws + off);      off += (size_t)NUM_CODES * D_OUT * 4;  // 2 MB
  char* CBbP = (char*)(ws + off);
  off += (size_t)NUM_CODES * D_IN * 2;                                       // 2 MB
  float* CBSQ = (float*)(ws + off);   off += (size_t)NUM_CODES * 4;
  float* HSQ = (float*)(ws + off);    off += (size_t)N_NODES * 4;
  off = (off + 255) & ~(size_t)255;
  float* candS = (float*)(ws + off);  off += (size_t)N_NODES * NCAND * 4;    // 6.4 MB
  int* candI = (int*)(ws + off);      off += (size_t)N_NODES * NCAND * 4;    // 6.4 MB
  int* cand4 = (int*)(ws + off);      off += (size_t)N_NODES * 4 * 4;        // 1.6 MB
  off = (off + 255) & ~(size_t)255;
  char* HbTail = ws + off;            off += 2 * 131072;                     // 256 KB
  // total ~224.3 MB

  const int row128 = (N_NODES + 127) / 128;  // 782

  k_rowsq<<<(NUM_CODES + 255) / 256, 256, 0, stream>>>(CB, NUM_CODES, CBSQ);
  k_cb2bf<<<NUM_CODES * 64 / 256, 256, 0, stream>>>(CB, CBbP);
  k_gemm_P<<<dim3(NUM_CODES / 64, D_OUT / 64), 256, 0, stream>>>(CB, HW, P);
  k_h_np<<<dim3(row128, D_IN / 128), 256, 0, stream>>>(X, LP, H, HbMain,
                                                       HbTail);
  k_rowsq<<<(N_NODES + 255) / 256, 256, 0, stream>>>(H, N_NODES, HSQ);
  k_mfma_cand<<<row128, 256, 0, stream>>>(HbMain, HbTail, CBbP, CBSQ, candS,
                                          candI);
  k_rescore<<<N_NODES / 16, 256, 0, stream>>>(H, CB, CBSQ, HSQ, candS, candI,
                                              cand4);
  k_out<<<N_NODES / 4, 256, 0, stream>>>(cand4, P, HB, OUT);
}